// Round 5
// baseline (783.055 us; speedup 1.0000x reference)
//
#include <hip/hip_runtime.h>
#include <cstdint>
#include <cstddef>

typedef unsigned long long u64;

#define CIN   512
#define H     38
#define W     50
#define HW    1900
#define PH    40
#define PW    52
#define XPL   (PH*PW)      // 2080
#define NA    17100
#define NSORT 20480
#define CHUNK 4096
#define PRE   6000
#define POST  300
#define NW    94           // ceil(6016/64)
#define MTS   6016
#define TOPN  6016
#define KSPLIT 3
#define KRANGE 1536        // 4608/3  — MUST stay 1536: round-1 bit-exact partial grouping

// prep section bases (256-thread blocks)
#define PB_PAD    0
#define PB_WT     4160     // 512*40*52/256
#define PB_WT2    5184     // +1024
#define PB_KEY    5312     // +128
#define PB_END    5325     // +13 (3328 threads >= 20480-17280)

__constant__ float c_AB[36] = {
  -37.254833f,  -82.50967f,   53.254833f,  98.50967f,
  -82.50967f,  -173.01933f,   98.50967f,  189.01933f,
 -173.01933f,  -354.03867f,  189.01933f,  370.03867f,
  -56.f, -56.f, 72.f, 72.f,
 -120.f,-120.f,136.f,136.f,
 -248.f,-248.f,264.f,264.f,
  -82.50967f,  -37.254833f,   98.50967f,  53.254833f,
 -173.01933f,  -82.50967f,   189.01933f,  98.50967f,
 -354.03867f, -173.01933f,   370.03867f, 189.01933f
};

// ============ fused prep: pad + wtrans + wt2prep + key pad-fill ============
__global__ __launch_bounds__(256) void prep_kernel(const float* __restrict__ x, float* __restrict__ xp,
                                                   const float* __restrict__ w1, float* __restrict__ wt,
                                                   const float* __restrict__ lw, const float* __restrict__ sw,
                                                   float* __restrict__ wt2, u64* __restrict__ keys) {
  __shared__ float tile[9][16][17];
  int bx = blockIdx.x;
  int tid = threadIdx.x;
  if (bx < PB_WT) {
    int idx = bx * 256 + tid;                     // exactly 512*40*52 elements
    int c   = idx / XPL;
    int rem = idx - c * XPL;
    int yy  = rem / PW;
    int xx  = rem - yy * PW;
    float v = 0.f;
    if (yy >= 1 && yy <= H && xx >= 1 && xx <= W)
      v = x[(size_t)c * HW + (yy - 1) * W + (xx - 1)];
    xp[idx] = v;
  } else if (bx < PB_WT2) {
    int b2 = bx - PB_WT;
    int o0 = (b2 & 31) * 16, i0 = (b2 >> 5) * 16;
    int tx = tid & 15, ty = tid >> 4;
    #pragma unroll
    for (int r = 0; r < 9; ++r)
      tile[r][tx][ty] = w1[((size_t)(o0 + ty) * CIN + (i0 + tx)) * 9 + r];
    __syncthreads();
    #pragma unroll
    for (int r = 0; r < 9; ++r)
      wt[((size_t)r * CIN + i0 + ty) * CIN + o0 + tx] = tile[r][ty][tx];
  } else if (bx < PB_KEY) {
    int t = (bx - PB_WT2) * 256 + tid;            // < 512*64
    int k = t >> 6, o = t & 63;
    float v = 0.f;
    if (o < 36)      v = lw[o * CIN + k];
    else if (o < 54) v = sw[(o - 36) * CIN + k];
    wt2[t] = v;
  } else {
    int idx = (bx - PB_KEY) * 256 + tid;
    int n = 17280 + idx;
    if (n < NSORT) keys[n] = ~0ull;
  }
}

// ============ conv1 implicit GEMM: 128x128 tile, 8x8 micro, fp32 ============
// k-chain order per output element identical to round-1 (bit-exact);
// KSPLIT=3 keeps round-1's partial-sum grouping.
__global__ __launch_bounds__(256, 1) void conv_gemm_kernel(const float* __restrict__ wt, const float* __restrict__ xp,
                                                           float* __restrict__ part) {
  __shared__ __align__(16) float As[16][128];
  __shared__ __align__(16) float Bs[16][128];
  const int tid   = threadIdx.x;
  const int obase = blockIdx.x * 128;
  const int pbase = blockIdx.y * 128;
  const int split = blockIdx.z;
  const int kbeg = split * KRANGE, kend = kbeg + KRANGE;

  const int ar = tid >> 4;
  const int ac = (tid & 15) * 8;
  const int wave = tid >> 6, lane = tid & 63;
  const int o_off = (wave & 1) * 64 + (lane & 7) * 8;
  const int p_off = (wave >> 1) * 64 + (lane >> 3) * 8;

  int poff[8]; int pok = 0;
  #pragma unroll
  for (int j = 0; j < 8; ++j) {
    int p = pbase + ac + j;
    int py = p / W, px = p - py * W;
    poff[j] = py * PW + px;
    if (p < HW) pok |= (1 << j);
  }

  float acc[8][8] = {};
  float av[8], bv[8];

  auto loadAB = [&](int k0) {
    int k = k0 + ar;
    const float* ap = &wt[(size_t)k * CIN + obase + ac];
    #pragma unroll
    for (int j = 0; j < 8; ++j) av[j] = ap[j];
    int i = k & 511;
    int r = k >> 9;
    int ky = r / 3, kx = r - ky * 3;
    const float* bp = &xp[(size_t)i * XPL + ky * PW + kx];
    #pragma unroll
    for (int j = 0; j < 8; ++j)
      bv[j] = (pok & (1 << j)) ? bp[poff[j]] : 0.f;
  };

  loadAB(kbeg);
  for (int k0 = kbeg; k0 < kend; k0 += 16) {
    __syncthreads();
    *(float4*)&As[ar][ac]     = make_float4(av[0], av[1], av[2], av[3]);
    *(float4*)&As[ar][ac + 4] = make_float4(av[4], av[5], av[6], av[7]);
    *(float4*)&Bs[ar][ac]     = make_float4(bv[0], bv[1], bv[2], bv[3]);
    *(float4*)&Bs[ar][ac + 4] = make_float4(bv[4], bv[5], bv[6], bv[7]);
    __syncthreads();
    if (k0 + 16 < kend) loadAB(k0 + 16);
    #pragma unroll
    for (int kk = 0; kk < 16; ++kk) {
      float4 a0 = *(const float4*)&As[kk][o_off];
      float4 a1 = *(const float4*)&As[kk][o_off + 4];
      float4 b0 = *(const float4*)&Bs[kk][p_off];
      float4 b1 = *(const float4*)&Bs[kk][p_off + 4];
      float ax[8] = {a0.x, a0.y, a0.z, a0.w, a1.x, a1.y, a1.z, a1.w};
      float bx[8] = {b0.x, b0.y, b0.z, b0.w, b1.x, b1.y, b1.z, b1.w};
      #pragma unroll
      for (int ii = 0; ii < 8; ++ii)
        #pragma unroll
        for (int jj = 0; jj < 8; ++jj)
          acc[ii][jj] += ax[ii] * bx[jj];
    }
  }
  float* dst = part + (size_t)split * CIN * HW;
  int p0 = pbase + p_off;
  #pragma unroll
  for (int ii = 0; ii < 8; ++ii) {
    int o = obase + o_off + ii;
    float* rowp = dst + (size_t)o * HW + p0;
    if (p0 + 7 < HW) {
      *(float4*)&rowp[0] = make_float4(acc[ii][0], acc[ii][1], acc[ii][2], acc[ii][3]);
      *(float4*)&rowp[4] = make_float4(acc[ii][4], acc[ii][5], acc[ii][6], acc[ii][7]);
    } else {
      #pragma unroll
      for (int jj = 0; jj < 8; ++jj) if (p0 + jj < HW) rowp[jj] = acc[ii][jj];
    }
  }
}

// ------------- h1 = relu(part0+part1+part2 + bias) — round-1 order -------------
__global__ __launch_bounds__(256) void reduce_relu_kernel(const float* __restrict__ part, const float* __restrict__ b1,
                                                          float* __restrict__ h1) {
  int idx = blockIdx.x * 256 + threadIdx.x;          // exactly 512*1900
  int o = idx / HW;
  float v = part[idx] + part[(size_t)CIN * HW + idx] + part[(size_t)2 * CIN * HW + idx] + b1[o];
  h1[idx] = v > 0.f ? v : 0.f;
}

// ====== heads GEMM (64x64 tile) fused with anchor decode + key generation ======
__global__ __launch_bounds__(256) void heads_decode_kernel(const float* __restrict__ wt2, const float* __restrict__ h1,
                                                           const float* __restrict__ lb, const float* __restrict__ sb,
                                                           float* __restrict__ roi, u64* __restrict__ keys) {
  __shared__ __align__(16) float As[16][64];
  __shared__ __align__(16) float Bs[16][64];
  __shared__ float c2s[64][65];
  const int tid   = threadIdx.x;
  const int pbase = blockIdx.x * 64;
  const int krow = tid >> 4;
  const int c4   = (tid & 15) * 4;
  const int to   = (tid & 15) * 4;
  const int tp   = (tid >> 4) * 4;
  float acc[4][4] = {};
  float av[4], bv[4];

  auto loadAB = [&](int k0) {
    int k = k0 + krow;
    const float4 a4 = *(const float4*)&wt2[k * 64 + c4];
    av[0] = a4.x; av[1] = a4.y; av[2] = a4.z; av[3] = a4.w;
    #pragma unroll
    for (int j = 0; j < 4; ++j) {
      int p = pbase + c4 + j;
      bv[j] = (p < HW) ? h1[(size_t)k * HW + p] : 0.f;
    }
  };

  loadAB(0);
  for (int k0 = 0; k0 < CIN; k0 += 16) {
    __syncthreads();
    *(float4*)&As[krow][c4] = make_float4(av[0], av[1], av[2], av[3]);
    *(float4*)&Bs[krow][c4] = make_float4(bv[0], bv[1], bv[2], bv[3]);
    __syncthreads();
    if (k0 + 16 < CIN) loadAB(k0 + 16);
    #pragma unroll
    for (int kk = 0; kk < 16; ++kk) {
      float4 a4 = *(const float4*)&As[kk][to];
      float4 b4 = *(const float4*)&Bs[kk][tp];
      float ar[4] = {a4.x, a4.y, a4.z, a4.w};
      float br[4] = {b4.x, b4.y, b4.z, b4.w};
      #pragma unroll
      for (int ii = 0; ii < 4; ++ii)
        #pragma unroll
        for (int jj = 0; jj < 4; ++jj)
          acc[ii][jj] += ar[ii] * br[jj];
    }
  }
  #pragma unroll
  for (int ii = 0; ii < 4; ++ii) {
    int o = to + ii;
    float bias = 0.f;
    if (o < 36) bias = lb[o]; else if (o < 54) bias = sb[o - 36];
    #pragma unroll
    for (int jj = 0; jj < 4; ++jj)
      c2s[o][tp + jj] = acc[ii][jj] + bias;
  }
  __syncthreads();
  // decode 64 positions x 9 anchors (arithmetic identical to round-1 decode)
  for (int t = tid; t < 576; t += 256) {
    int pl = t / 9, a = t - pl * 9;
    int p = pbase + pl;
    int n = p * 9 + a;
    if (p >= HW) { if (p < 1920) keys[n] = ~0ull; continue; }
    unsigned y = (unsigned)p / 50u;
    unsigned x = (unsigned)p - y * 50u;
    float dy = c2s[a * 4 + 0][pl];
    float dx = c2s[a * 4 + 1][pl];
    float dh = c2s[a * 4 + 2][pl];
    float dw = c2s[a * 4 + 3][pl];
    float fg = c2s[37 + a * 2][pl];
    float sy = (float)(y * 16u), sx = (float)(x * 16u);
    float ay1 = sy + c_AB[a * 4 + 0], ax1 = sx + c_AB[a * 4 + 1];
    float ay2 = sy + c_AB[a * 4 + 2], ax2 = sx + c_AB[a * 4 + 3];
    float ahh = ay2 - ay1, aww = ax2 - ax1;
    float acy = ay1 + 0.5f * ahh, acx = ax1 + 0.5f * aww;
    float cy = dy * ahh + acy, cx = dx * aww + acx;
    float hh = expf(dh) * ahh, ww = expf(dw) * aww;
    float y1 = cy - 0.5f * hh, x1 = cx - 0.5f * ww;
    float y2 = cy + 0.5f * hh, x2 = cx + 0.5f * ww;
    y1 = fminf(fmaxf(y1, 0.f), 608.f); x1 = fminf(fmaxf(x1, 0.f), 800.f);
    y2 = fminf(fmaxf(y2, 0.f), 608.f); x2 = fminf(fmaxf(x2, 0.f), 800.f);
    *(float4*)&roi[(size_t)n * 4] = make_float4(y1, x1, y2, x2);
    bool valid = ((y2 - y1) >= 16.f) && ((x2 - x1) >= 16.f);
    float sc = valid ? fg : -__builtin_huge_valf();
    unsigned m = __float_as_uint(sc);
    m = (m & 0x80000000u) ? ~m : (m | 0x80000000u);
    unsigned km = ~m;
    keys[n] = ((u64)km << 32) | (unsigned)n;
  }
}

// ----------------- LDS bitonic sort of one 4096 chunk (asc) -------------------
__global__ __launch_bounds__(1024) void sort_kernel(u64* __restrict__ keys) {
  __shared__ u64 s[CHUNK];
  const int tid = threadIdx.x;
  u64* base = keys + (size_t)blockIdx.x * CHUNK;
  #pragma unroll
  for (int i = 0; i < 4; ++i) s[tid + i * 1024] = base[tid + i * 1024];
  __syncthreads();
  for (int k = 2; k <= CHUNK; k <<= 1) {
    for (int j = k >> 1; j > 0; j >>= 1) {
      #pragma unroll
      for (int it = 0; it < 2; ++it) {
        int t = tid + it * 1024;                    // pair index 0..2047
        int i = ((t & ~(j - 1)) << 1) | (t & (j - 1));
        int l = i | j;
        bool up = ((i & k) == 0);
        u64 xa = s[i], xb = s[l];
        if ((xa > xb) == up) { s[i] = xb; s[l] = xa; }
      }
      __syncthreads();
    }
  }
  #pragma unroll
  for (int i = 0; i < 4; ++i) base[tid + i * 1024] = s[tid + i * 1024];
}

// ------------------------------ merge-path merges ------------------------------
__device__ inline void merge_path(const u64* __restrict__ A, int nA, const u64* __restrict__ B, int nB,
                                  u64* __restrict__ dst, int d0, int cnt, int outLimit) {
  if (d0 >= outLimit || d0 >= nA + nB) return;
  int lo = d0 > nB ? d0 - nB : 0;
  int hi = d0 < nA ? d0 : nA;
  while (lo < hi) {
    int mid = (lo + hi) >> 1;
    if (A[mid] <= B[d0 - 1 - mid]) lo = mid + 1; else hi = mid;
  }
  int i = lo, j = d0 - lo;
  int end = d0 + cnt;
  if (end > nA + nB) end = nA + nB;
  if (end > outLimit) end = outLimit;
  for (int q = d0; q < end; ++q) {
    u64 v;
    if (i < nA && (j >= nB || A[i] <= B[j])) v = A[i++]; else v = B[j++];
    dst[q] = v;
  }
}
// L1: (c0,c1)->tmp[0..], (c2,c3)->tmp[8192..], each truncated to top-6016
__global__ __launch_bounds__(256) void merge1_kernel(const u64* __restrict__ keys, u64* __restrict__ tmp) {
  int pair = blockIdx.y;
  int gid = blockIdx.x * 256 + threadIdx.x;
  const u64* A = keys + (size_t)pair * 8192;
  merge_path(A, CHUNK, A + CHUNK, CHUNK, tmp + (size_t)pair * 8192, gid * 16, 16, TOPN);
}
// L2: (6016,6016) -> tmp2
__global__ __launch_bounds__(256) void merge2_kernel(const u64* __restrict__ tmp, u64* __restrict__ tmp2) {
  int gid = blockIdx.x * 256 + threadIdx.x;
  merge_path(tmp, TOPN, tmp + 8192, TOPN, tmp2, gid * 16, 16, TOPN);
}
// L3: (6016, chunk4) -> topk
__global__ __launch_bounds__(256) void merge3_kernel(const u64* __restrict__ tmp2, const u64* __restrict__ keys,
                                                     u64* __restrict__ topk) {
  int gid = blockIdx.x * 256 + threadIdx.x;
  merge_path(tmp2, TOPN, keys + 16384, CHUNK, topk, gid * 16, 16, TOPN);
}

// ===== fused gather+mask: per (word w, i-block): suppression bits + validity =====
__global__ __launch_bounds__(256) void mask_kernel(const u64* __restrict__ topk, const float* __restrict__ roi,
                                                   u64* __restrict__ MT, u64* __restrict__ valw) {
  __shared__ float jy1[64], jx1[64], jy2[64], jx2[64], jar[64];
  int w = blockIdx.x;
  int tid = threadIdx.x;
  if (tid < 64) {
    int jj = w * 64 + tid;
    u64 key = (jj < TOPN) ? topk[jj] : ~0ull;
    unsigned idx = (unsigned)key;
    float4 b = make_float4(0.f, 0.f, 0.f, 0.f);
    if (idx < NA) b = *(const float4*)&roi[(size_t)idx * 4];
    jy1[tid] = b.x; jx1[tid] = b.y; jy2[tid] = b.z; jx2[tid] = b.w;
    jar[tid] = (b.z - b.x) * (b.w - b.y);
    bool jv = (jj < PRE) && ((unsigned)(key >> 32) < 0xFF800000u);
    u64 mvote = __ballot(jv);
    if (tid == 0 && blockIdx.y == 0) valw[w] = mvote;
  }
  __syncthreads();
  int i = blockIdx.y * 256 + tid;
  if (i >= MTS) return;
  u64 bits = 0;
  if (i < PRE) {
    u64 ikey = topk[i];
    unsigned iidx = (unsigned)ikey;
    float4 bi = make_float4(0.f, 0.f, 0.f, 0.f);
    if (iidx < NA) bi = *(const float4*)&roi[(size_t)iidx * 4];
    float ai = (bi.z - bi.x) * (bi.w - bi.y);
    int jbase = w * 64;
    int jend = jbase + 64; if (jend > PRE) jend = PRE;
    int jst = jbase > i + 1 ? jbase : i + 1;
    for (int j = jst; j < jend; ++j) {
      int jl = j - jbase;
      float ty1 = fmaxf(bi.x, jy1[jl]);
      float tx1 = fmaxf(bi.y, jx1[jl]);
      float ty2 = fminf(bi.z, jy2[jl]);
      float tx2 = fminf(bi.w, jx2[jl]);
      float ih = ty2 - ty1; if (ih < 0.f) ih = 0.f;
      float iw = tx2 - tx1; if (iw < 0.f) iw = 0.f;
      float inter = ih * iw;
      float denom = ai + jar[jl] - inter;
      if (denom < 1e-9f) denom = 1e-9f;
      if (inter / denom > 0.7f) bits |= (1ull << jl);
    }
  }
  MT[(size_t)w * MTS + i] = bits;
}

__device__ inline u64 shfl_u64(u64 v, int src) {
  int lo = __shfl((int)(unsigned)(v & 0xffffffffull), src, 64);
  int hi = __shfl((int)(unsigned)(v >> 32), src, 64);
  return ((u64)(unsigned)hi << 32) | (unsigned)lo;
}
__device__ inline u64 wave_or_u64(u64 x) {
  #pragma unroll
  for (int d = 1; d < 64; d <<= 1) {
    int lo = __shfl_xor((int)(unsigned)(x & 0xffffffffull), d, 64);
    int hi = __shfl_xor((int)(x >> 32), d, 64);
    x |= ((u64)(unsigned)hi << 32) | (unsigned)lo;
  }
  return x;
}

// ------------- single-wave greedy NMS scan + write first 300 kept --------------
__global__ __launch_bounds__(64) void nms_scan_kernel(const u64* __restrict__ MT, const u64* __restrict__ valw,
                                                      const u64* __restrict__ topk, const float* __restrict__ roi,
                                                      float* __restrict__ out) {
  __shared__ u64 removed[NW];
  __shared__ int keepids[POST];
  const int lane = threadIdx.x;
  for (int wk = lane; wk < NW; wk += 64) removed[wk] = 0;
  __syncthreads();
  int kept = 0;
  bool done = false;
  for (int g = 0; g < NW && !done; ++g) {
    int row = g * 64 + lane;
    u64 cur = MT[(size_t)g * MTS + row];               // row < 6016 always in-bounds
    u64 v = valw[g] & ~removed[g];
    u64 kb = 0;
    while (v) {
      int c = __builtin_ctzll(v);
      if (lane == 0) keepids[kept] = g * 64 + c;
      kb |= (1ull << c);
      ++kept;
      if (kept >= POST) { done = true; break; }
      u64 cw = shfl_u64(cur, c);
      v &= ~cw;
      u64 above = (c == 63) ? 0ull : (~0ull << (c + 1));
      v &= above;
    }
    if (!done && kb) {
      for (int wk = g + 1; wk < NW; ++wk) {
        u64 x = MT[(size_t)wk * MTS + g * 64 + lane];   // coalesced 512B row
        if (!((kb >> lane) & 1ull)) x = 0;
        x = wave_or_u64(x);
        if (lane == 0) removed[wk] |= x;
      }
    }
    __syncthreads();
  }
  __syncthreads();
  int kmax = kept < POST ? kept : POST;
  for (int rr = lane; rr < kmax; rr += 64) {
    unsigned idx = (unsigned)topk[keepids[rr]];
    float4 b = *(const float4*)&roi[(size_t)idx * 4];
    *(float4*)&out[(size_t)rr * 4] = b;
  }
}

extern "C" void kernel_launch(void* const* d_in, const int* in_sizes, int n_in,
                              void* d_out, int out_size, void* d_ws, size_t ws_size,
                              hipStream_t stream) {
  (void)in_sizes; (void)n_in; (void)ws_size;
  const float* x  = (const float*)d_in[0];
  const float* w1 = (const float*)d_in[1];
  const float* b1 = (const float*)d_in[2];
  const float* lw = (const float*)d_in[3];
  const float* lb = (const float*)d_in[4];
  const float* sw = (const float*)d_in[5];
  const float* sb = (const float*)d_in[6];
  float* out = (float*)d_out;

  char* wp = (char*)d_ws;
  auto alloc = [&](size_t b) -> void* { void* p = wp; wp += (b + 255) & ~(size_t)255; return p; };
  float* xp   = (float*)alloc((size_t)CIN * XPL * 4);            // 4.26 MB
  float* wt   = (float*)alloc((size_t)4608 * CIN * 4);           // 9.44 MB
  float* part = (float*)alloc((size_t)KSPLIT * CIN * HW * 4);    // 11.7 MB
  float* h1   = (float*)alloc((size_t)CIN * HW * 4);             // 3.89 MB
  float* wt2  = (float*)alloc((size_t)CIN * 64 * 4);
  float* roi  = (float*)alloc((size_t)NA * 4 * 4);
  u64*   keys = (u64*)alloc((size_t)NSORT * 8);
  u64*   tmp  = (u64*)alloc((size_t)24576 * 8);
  u64*   topk = (u64*)alloc((size_t)TOPN * 8);
  u64*   valw = (u64*)alloc((size_t)NW * 8);
  u64*   MT   = (u64*)alloc((size_t)NW * MTS * 8);               // 4.52 MB

  hipMemsetAsync(d_out, 0, (size_t)out_size * 4, stream);

  prep_kernel<<<PB_END, 256, 0, stream>>>(x, xp, w1, wt, lw, sw, wt2, keys);
  conv_gemm_kernel<<<dim3(4, 15, KSPLIT), 256, 0, stream>>>(wt, xp, part);
  reduce_relu_kernel<<<(CIN * HW) / 256, 256, 0, stream>>>(part, b1, h1);
  heads_decode_kernel<<<30, 256, 0, stream>>>(wt2, h1, lb, sb, roi, keys);
  sort_kernel<<<5, 1024, 0, stream>>>(keys);
  merge1_kernel<<<dim3(2, 2), 256, 0, stream>>>(keys, tmp);
  merge2_kernel<<<2, 256, 0, stream>>>(tmp, tmp + 16384);
  merge3_kernel<<<2, 256, 0, stream>>>(tmp + 16384, keys, topk);
  mask_kernel<<<dim3(NW, 24), 256, 0, stream>>>(topk, roi, MT, valw);
  nms_scan_kernel<<<1, 64, 0, stream>>>(MT, valw, topk, roi, out);
}

// Round 6
// 593.426 us; speedup vs baseline: 1.3195x; 1.3195x over previous
//
#include <hip/hip_runtime.h>
#include <cstdint>
#include <cstddef>

typedef unsigned long long u64;

#define CIN   512
#define H     38
#define W     50
#define HW    1900
#define PH    40
#define PW    52
#define XPL   (PH*PW)      // 2080
#define NA    17100
#define NSORT 20480
#define CHUNK 4096
#define PRE   6000
#define POST  300
#define NW    94           // ceil(6016/64)
#define MTS   6016
#define TOPN  6016
#define KSPLIT 3
#define KRANGE 1536        // 4608/3  — MUST stay 1536: round-1 bit-exact partial grouping

// prep section bases (256-thread blocks)
#define PB_PAD    0
#define PB_WT     4160     // 512*40*52/256
#define PB_WT2    5184     // +1024
#define PB_KEY    5312     // +128
#define PB_END    5325     // +13 (3328 threads >= 20480-17280)

__constant__ float c_AB[36] = {
  -37.254833f,  -82.50967f,   53.254833f,  98.50967f,
  -82.50967f,  -173.01933f,   98.50967f,  189.01933f,
 -173.01933f,  -354.03867f,  189.01933f,  370.03867f,
  -56.f, -56.f, 72.f, 72.f,
 -120.f,-120.f,136.f,136.f,
 -248.f,-248.f,264.f,264.f,
  -82.50967f,  -37.254833f,   98.50967f,  53.254833f,
 -173.01933f,  -82.50967f,   189.01933f,  98.50967f,
 -354.03867f, -173.01933f,   370.03867f, 189.01933f
};

// ============ fused prep: pad + wtrans + wt2prep + key pad-fill ============
__global__ __launch_bounds__(256) void prep_kernel(const float* __restrict__ x, float* __restrict__ xp,
                                                   const float* __restrict__ w1, float* __restrict__ wt,
                                                   const float* __restrict__ lw, const float* __restrict__ sw,
                                                   float* __restrict__ wt2, u64* __restrict__ keys) {
  __shared__ float tile[9][16][17];
  int bx = blockIdx.x;
  int tid = threadIdx.x;
  if (bx < PB_WT) {
    int idx = bx * 256 + tid;                     // exactly 512*40*52 elements
    int c   = idx / XPL;
    int rem = idx - c * XPL;
    int yy  = rem / PW;
    int xx  = rem - yy * PW;
    float v = 0.f;
    if (yy >= 1 && yy <= H && xx >= 1 && xx <= W)
      v = x[(size_t)c * HW + (yy - 1) * W + (xx - 1)];
    xp[idx] = v;
  } else if (bx < PB_WT2) {
    int b2 = bx - PB_WT;
    int o0 = (b2 & 31) * 16, i0 = (b2 >> 5) * 16;
    int tx = tid & 15, ty = tid >> 4;
    #pragma unroll
    for (int r = 0; r < 9; ++r)
      tile[r][tx][ty] = w1[((size_t)(o0 + ty) * CIN + (i0 + tx)) * 9 + r];
    __syncthreads();
    #pragma unroll
    for (int r = 0; r < 9; ++r)
      wt[((size_t)r * CIN + i0 + ty) * CIN + o0 + tx] = tile[r][ty][tx];
  } else if (bx < PB_KEY) {
    int t = (bx - PB_WT2) * 256 + tid;            // < 512*64
    int k = t >> 6, o = t & 63;
    float v = 0.f;
    if (o < 36)      v = lw[o * CIN + k];
    else if (o < 54) v = sw[(o - 36) * CIN + k];
    wt2[t] = v;
  } else {
    int idx = (bx - PB_KEY) * 256 + tid;
    int n = 17280 + idx;
    if (n < NSORT) keys[n] = ~0ull;
  }
}

// ============ conv1 implicit GEMM: 128x128 tile, 8x8 micro, fp32 ============
// k-chain order per output element identical to round-1 (bit-exact);
// KSPLIT=3 keeps round-1's partial-sum grouping.
__global__ __launch_bounds__(256, 1) void conv_gemm_kernel(const float* __restrict__ wt, const float* __restrict__ xp,
                                                           float* __restrict__ part) {
  __shared__ __align__(16) float As[16][128];
  __shared__ __align__(16) float Bs[16][128];
  const int tid   = threadIdx.x;
  const int obase = blockIdx.x * 128;
  const int pbase = blockIdx.y * 128;
  const int split = blockIdx.z;
  const int kbeg = split * KRANGE, kend = kbeg + KRANGE;

  const int ar = tid >> 4;
  const int ac = (tid & 15) * 8;
  const int wave = tid >> 6, lane = tid & 63;
  const int o_off = (wave & 1) * 64 + (lane & 7) * 8;
  const int p_off = (wave >> 1) * 64 + (lane >> 3) * 8;

  int poff[8]; int pok = 0;
  #pragma unroll
  for (int j = 0; j < 8; ++j) {
    int p = pbase + ac + j;
    int py = p / W, px = p - py * W;
    poff[j] = py * PW + px;
    if (p < HW) pok |= (1 << j);
  }

  float acc[8][8] = {};
  float av[8], bv[8];

  auto loadAB = [&](int k0) {
    int k = k0 + ar;
    const float* ap = &wt[(size_t)k * CIN + obase + ac];
    #pragma unroll
    for (int j = 0; j < 8; ++j) av[j] = ap[j];
    int i = k & 511;
    int r = k >> 9;
    int ky = r / 3, kx = r - ky * 3;
    const float* bp = &xp[(size_t)i * XPL + ky * PW + kx];
    #pragma unroll
    for (int j = 0; j < 8; ++j)
      bv[j] = (pok & (1 << j)) ? bp[poff[j]] : 0.f;
  };

  loadAB(kbeg);
  for (int k0 = kbeg; k0 < kend; k0 += 16) {
    __syncthreads();
    *(float4*)&As[ar][ac]     = make_float4(av[0], av[1], av[2], av[3]);
    *(float4*)&As[ar][ac + 4] = make_float4(av[4], av[5], av[6], av[7]);
    *(float4*)&Bs[ar][ac]     = make_float4(bv[0], bv[1], bv[2], bv[3]);
    *(float4*)&Bs[ar][ac + 4] = make_float4(bv[4], bv[5], bv[6], bv[7]);
    __syncthreads();
    if (k0 + 16 < kend) loadAB(k0 + 16);
    #pragma unroll
    for (int kk = 0; kk < 16; ++kk) {
      float4 a0 = *(const float4*)&As[kk][o_off];
      float4 a1 = *(const float4*)&As[kk][o_off + 4];
      float4 b0 = *(const float4*)&Bs[kk][p_off];
      float4 b1 = *(const float4*)&Bs[kk][p_off + 4];
      float ax[8] = {a0.x, a0.y, a0.z, a0.w, a1.x, a1.y, a1.z, a1.w};
      float bx[8] = {b0.x, b0.y, b0.z, b0.w, b1.x, b1.y, b1.z, b1.w};
      #pragma unroll
      for (int ii = 0; ii < 8; ++ii)
        #pragma unroll
        for (int jj = 0; jj < 8; ++jj)
          acc[ii][jj] += ax[ii] * bx[jj];
    }
  }
  float* dst = part + (size_t)split * CIN * HW;
  int p0 = pbase + p_off;
  #pragma unroll
  for (int ii = 0; ii < 8; ++ii) {
    int o = obase + o_off + ii;
    float* rowp = dst + (size_t)o * HW + p0;
    if (p0 + 7 < HW) {
      *(float4*)&rowp[0] = make_float4(acc[ii][0], acc[ii][1], acc[ii][2], acc[ii][3]);
      *(float4*)&rowp[4] = make_float4(acc[ii][4], acc[ii][5], acc[ii][6], acc[ii][7]);
    } else {
      #pragma unroll
      for (int jj = 0; jj < 8; ++jj) if (p0 + jj < HW) rowp[jj] = acc[ii][jj];
    }
  }
}

// ------------- h1 = relu(part0+part1+part2 + bias) — round-1 order -------------
__global__ __launch_bounds__(256) void reduce_relu_kernel(const float* __restrict__ part, const float* __restrict__ b1,
                                                          float* __restrict__ h1) {
  int idx = blockIdx.x * 256 + threadIdx.x;          // exactly 512*1900
  int o = idx / HW;
  float v = part[idx] + part[(size_t)CIN * HW + idx] + part[(size_t)2 * CIN * HW + idx] + b1[o];
  h1[idx] = v > 0.f ? v : 0.f;
}

// ====== heads GEMM (64x64 tile) fused with anchor decode + key generation ======
__global__ __launch_bounds__(256) void heads_decode_kernel(const float* __restrict__ wt2, const float* __restrict__ h1,
                                                           const float* __restrict__ lb, const float* __restrict__ sb,
                                                           float* __restrict__ roi, u64* __restrict__ keys) {
  __shared__ __align__(16) float As[16][64];
  __shared__ __align__(16) float Bs[16][64];
  __shared__ float c2s[64][65];
  const int tid   = threadIdx.x;
  const int pbase = blockIdx.x * 64;
  const int krow = tid >> 4;
  const int c4   = (tid & 15) * 4;
  const int to   = (tid & 15) * 4;
  const int tp   = (tid >> 4) * 4;
  float acc[4][4] = {};
  float av[4], bv[4];

  auto loadAB = [&](int k0) {
    int k = k0 + krow;
    const float4 a4 = *(const float4*)&wt2[k * 64 + c4];
    av[0] = a4.x; av[1] = a4.y; av[2] = a4.z; av[3] = a4.w;
    #pragma unroll
    for (int j = 0; j < 4; ++j) {
      int p = pbase + c4 + j;
      bv[j] = (p < HW) ? h1[(size_t)k * HW + p] : 0.f;
    }
  };

  loadAB(0);
  for (int k0 = 0; k0 < CIN; k0 += 16) {
    __syncthreads();
    *(float4*)&As[krow][c4] = make_float4(av[0], av[1], av[2], av[3]);
    *(float4*)&Bs[krow][c4] = make_float4(bv[0], bv[1], bv[2], bv[3]);
    __syncthreads();
    if (k0 + 16 < CIN) loadAB(k0 + 16);
    #pragma unroll
    for (int kk = 0; kk < 16; ++kk) {
      float4 a4 = *(const float4*)&As[kk][to];
      float4 b4 = *(const float4*)&Bs[kk][tp];
      float ar[4] = {a4.x, a4.y, a4.z, a4.w};
      float br[4] = {b4.x, b4.y, b4.z, b4.w};
      #pragma unroll
      for (int ii = 0; ii < 4; ++ii)
        #pragma unroll
        for (int jj = 0; jj < 4; ++jj)
          acc[ii][jj] += ar[ii] * br[jj];
    }
  }
  #pragma unroll
  for (int ii = 0; ii < 4; ++ii) {
    int o = to + ii;
    float bias = 0.f;
    if (o < 36) bias = lb[o]; else if (o < 54) bias = sb[o - 36];
    #pragma unroll
    for (int jj = 0; jj < 4; ++jj)
      c2s[o][tp + jj] = acc[ii][jj] + bias;
  }
  __syncthreads();
  // decode 64 positions x 9 anchors (arithmetic identical to round-1 decode)
  for (int t = tid; t < 576; t += 256) {
    int pl = t / 9, a = t - pl * 9;
    int p = pbase + pl;
    int n = p * 9 + a;
    if (p >= HW) { if (p < 1920) keys[n] = ~0ull; continue; }
    unsigned y = (unsigned)p / 50u;
    unsigned x = (unsigned)p - y * 50u;
    float dy = c2s[a * 4 + 0][pl];
    float dx = c2s[a * 4 + 1][pl];
    float dh = c2s[a * 4 + 2][pl];
    float dw = c2s[a * 4 + 3][pl];
    float fg = c2s[37 + a * 2][pl];
    float sy = (float)(y * 16u), sx = (float)(x * 16u);
    float ay1 = sy + c_AB[a * 4 + 0], ax1 = sx + c_AB[a * 4 + 1];
    float ay2 = sy + c_AB[a * 4 + 2], ax2 = sx + c_AB[a * 4 + 3];
    float ahh = ay2 - ay1, aww = ax2 - ax1;
    float acy = ay1 + 0.5f * ahh, acx = ax1 + 0.5f * aww;
    float cy = dy * ahh + acy, cx = dx * aww + acx;
    float hh = expf(dh) * ahh, ww = expf(dw) * aww;
    float y1 = cy - 0.5f * hh, x1 = cx - 0.5f * ww;
    float y2 = cy + 0.5f * hh, x2 = cx + 0.5f * ww;
    y1 = fminf(fmaxf(y1, 0.f), 608.f); x1 = fminf(fmaxf(x1, 0.f), 800.f);
    y2 = fminf(fmaxf(y2, 0.f), 608.f); x2 = fminf(fmaxf(x2, 0.f), 800.f);
    *(float4*)&roi[(size_t)n * 4] = make_float4(y1, x1, y2, x2);
    bool valid = ((y2 - y1) >= 16.f) && ((x2 - x1) >= 16.f);
    float sc = valid ? fg : -__builtin_huge_valf();
    unsigned m = __float_as_uint(sc);
    m = (m & 0x80000000u) ? ~m : (m | 0x80000000u);
    unsigned km = ~m;
    keys[n] = ((u64)km << 32) | (unsigned)n;
  }
}

// ----------------- LDS bitonic sort of one 4096 chunk (asc) -------------------
__global__ __launch_bounds__(1024) void sort_kernel(u64* __restrict__ keys) {
  __shared__ u64 s[CHUNK];
  const int tid = threadIdx.x;
  u64* base = keys + (size_t)blockIdx.x * CHUNK;
  #pragma unroll
  for (int i = 0; i < 4; ++i) s[tid + i * 1024] = base[tid + i * 1024];
  __syncthreads();
  for (int k = 2; k <= CHUNK; k <<= 1) {
    for (int j = k >> 1; j > 0; j >>= 1) {
      #pragma unroll
      for (int it = 0; it < 2; ++it) {
        int t = tid + it * 1024;                    // pair index 0..2047
        int i = ((t & ~(j - 1)) << 1) | (t & (j - 1));
        int l = i | j;
        bool up = ((i & k) == 0);
        u64 xa = s[i], xb = s[l];
        if ((xa > xb) == up) { s[i] = xb; s[l] = xa; }
      }
      __syncthreads();
    }
  }
  #pragma unroll
  for (int i = 0; i < 4; ++i) base[tid + i * 1024] = s[tid + i * 1024];
}

// ------------------------------ merge-path merges ------------------------------
__device__ inline void merge_path(const u64* __restrict__ A, int nA, const u64* __restrict__ B, int nB,
                                  u64* __restrict__ dst, int d0, int cnt, int outLimit) {
  if (d0 >= outLimit || d0 >= nA + nB) return;
  int lo = d0 > nB ? d0 - nB : 0;
  int hi = d0 < nA ? d0 : nA;
  while (lo < hi) {
    int mid = (lo + hi) >> 1;
    if (A[mid] <= B[d0 - 1 - mid]) lo = mid + 1; else hi = mid;
  }
  int i = lo, j = d0 - lo;
  int end = d0 + cnt;
  if (end > nA + nB) end = nA + nB;
  if (end > outLimit) end = outLimit;
  for (int q = d0; q < end; ++q) {
    u64 v;
    if (i < nA && (j >= nB || A[i] <= B[j])) v = A[i++]; else v = B[j++];
    dst[q] = v;
  }
}
// L1: (c0,c1)->tmp[0..], (c2,c3)->tmp[8192..], each truncated to top-6016
__global__ __launch_bounds__(256) void merge1_kernel(const u64* __restrict__ keys, u64* __restrict__ tmp) {
  int pair = blockIdx.y;
  int gid = blockIdx.x * 256 + threadIdx.x;
  const u64* A = keys + (size_t)pair * 8192;
  merge_path(A, CHUNK, A + CHUNK, CHUNK, tmp + (size_t)pair * 8192, gid * 16, 16, TOPN);
}
// L2: (6016,6016) -> tmp2
__global__ __launch_bounds__(256) void merge2_kernel(const u64* __restrict__ tmp, u64* __restrict__ tmp2) {
  int gid = blockIdx.x * 256 + threadIdx.x;
  merge_path(tmp, TOPN, tmp + 8192, TOPN, tmp2, gid * 16, 16, TOPN);
}
// L3: (6016, chunk4) -> topk
__global__ __launch_bounds__(256) void merge3_kernel(const u64* __restrict__ tmp2, const u64* __restrict__ keys,
                                                     u64* __restrict__ topk) {
  int gid = blockIdx.x * 256 + threadIdx.x;
  merge_path(tmp2, TOPN, keys + 16384, CHUNK, topk, gid * 16, 16, TOPN);
}

// ===== fused gather+mask: per (word w, i-block): suppression bits + validity =====
__global__ __launch_bounds__(256) void mask_kernel(const u64* __restrict__ topk, const float* __restrict__ roi,
                                                   u64* __restrict__ MT, u64* __restrict__ valw) {
  __shared__ float jy1[64], jx1[64], jy2[64], jx2[64], jar[64];
  int w = blockIdx.x;
  int tid = threadIdx.x;
  if (tid < 64) {
    int jj = w * 64 + tid;
    u64 key = (jj < TOPN) ? topk[jj] : ~0ull;
    unsigned idx = (unsigned)key;
    float4 b = make_float4(0.f, 0.f, 0.f, 0.f);
    if (idx < NA) b = *(const float4*)&roi[(size_t)idx * 4];
    jy1[tid] = b.x; jx1[tid] = b.y; jy2[tid] = b.z; jx2[tid] = b.w;
    jar[tid] = (b.z - b.x) * (b.w - b.y);
    bool jv = (jj < PRE) && ((unsigned)(key >> 32) < 0xFF800000u);
    u64 mvote = __ballot(jv);
    if (tid == 0 && blockIdx.y == 0) valw[w] = mvote;
  }
  __syncthreads();
  int i = blockIdx.y * 256 + tid;
  if (i >= MTS) return;
  u64 bits = 0;
  if (i < PRE) {
    u64 ikey = topk[i];
    unsigned iidx = (unsigned)ikey;
    float4 bi = make_float4(0.f, 0.f, 0.f, 0.f);
    if (iidx < NA) bi = *(const float4*)&roi[(size_t)iidx * 4];
    float ai = (bi.z - bi.x) * (bi.w - bi.y);
    int jbase = w * 64;
    int jend = jbase + 64; if (jend > PRE) jend = PRE;
    int jst = jbase > i + 1 ? jbase : i + 1;
    for (int j = jst; j < jend; ++j) {
      int jl = j - jbase;
      float ty1 = fmaxf(bi.x, jy1[jl]);
      float tx1 = fmaxf(bi.y, jx1[jl]);
      float ty2 = fminf(bi.z, jy2[jl]);
      float tx2 = fminf(bi.w, jx2[jl]);
      float ih = ty2 - ty1; if (ih < 0.f) ih = 0.f;
      float iw = tx2 - tx1; if (iw < 0.f) iw = 0.f;
      float inter = ih * iw;
      float denom = ai + jar[jl] - inter;
      if (denom < 1e-9f) denom = 1e-9f;
      if (inter / denom > 0.7f) bits |= (1ull << jl);
    }
  }
  MT[(size_t)w * MTS + i] = bits;
}

__device__ inline u64 shfl_u64(u64 v, int src) {
  int lo = __shfl((int)(unsigned)(v & 0xffffffffull), src, 64);
  int hi = __shfl((int)(unsigned)(v >> 32), src, 64);
  return ((u64)(unsigned)hi << 32) | (unsigned)lo;
}

// ------------- single-wave greedy NMS scan + write first 300 kept --------------
// removed-update loop: lane-parallel over future words wk (round-1 form) —
// 64 scattered loads in flight beats serial coalesced rows by ~10x (R5 lesson).
__global__ __launch_bounds__(64) void nms_scan_kernel(const u64* __restrict__ MT, const u64* __restrict__ valw,
                                                      const u64* __restrict__ topk, const float* __restrict__ roi,
                                                      float* __restrict__ out) {
  __shared__ u64 removed[NW];
  __shared__ int keepids[POST];
  const int lane = threadIdx.x;
  for (int wk = lane; wk < NW; wk += 64) removed[wk] = 0;
  __syncthreads();
  int kept = 0;
  bool done = false;
  for (int g = 0; g < NW && !done; ++g) {
    int row = g * 64 + lane;
    u64 cur = MT[(size_t)g * MTS + row];               // row < 6016 always in-bounds
    u64 v = valw[g] & ~removed[g];
    u64 kb = 0;
    while (v) {
      int c = __builtin_ctzll(v);
      if (lane == 0) keepids[kept] = g * 64 + c;
      kb |= (1ull << c);
      ++kept;
      if (kept >= POST) { done = true; break; }
      u64 cw = shfl_u64(cur, c);
      v &= ~cw;
      u64 above = (c == 63) ? 0ull : (~0ull << (c + 1));
      v &= above;
    }
    if (!done && kb) {
      __syncthreads();
      for (int wk = g + 1 + lane; wk < NW; wk += 64) {
        u64 acc2 = removed[wk];
        u64 m = kb;
        while (m) {
          int b = __builtin_ctzll(m); m &= m - 1;
          acc2 |= MT[(size_t)wk * MTS + g * 64 + b];
        }
        removed[wk] = acc2;
      }
      __syncthreads();
    }
  }
  __syncthreads();
  int kmax = kept < POST ? kept : POST;
  for (int rr = lane; rr < kmax; rr += 64) {
    unsigned idx = (unsigned)topk[keepids[rr]];
    float4 b = *(const float4*)&roi[(size_t)idx * 4];
    *(float4*)&out[(size_t)rr * 4] = b;
  }
}

extern "C" void kernel_launch(void* const* d_in, const int* in_sizes, int n_in,
                              void* d_out, int out_size, void* d_ws, size_t ws_size,
                              hipStream_t stream) {
  (void)in_sizes; (void)n_in; (void)ws_size;
  const float* x  = (const float*)d_in[0];
  const float* w1 = (const float*)d_in[1];
  const float* b1 = (const float*)d_in[2];
  const float* lw = (const float*)d_in[3];
  const float* lb = (const float*)d_in[4];
  const float* sw = (const float*)d_in[5];
  const float* sb = (const float*)d_in[6];
  float* out = (float*)d_out;

  char* wp = (char*)d_ws;
  auto alloc = [&](size_t b) -> void* { void* p = wp; wp += (b + 255) & ~(size_t)255; return p; };
  float* xp   = (float*)alloc((size_t)CIN * XPL * 4);            // 4.26 MB
  float* wt   = (float*)alloc((size_t)4608 * CIN * 4);           // 9.44 MB
  float* part = (float*)alloc((size_t)KSPLIT * CIN * HW * 4);    // 11.7 MB
  float* h1   = (float*)alloc((size_t)CIN * HW * 4);             // 3.89 MB
  float* wt2  = (float*)alloc((size_t)CIN * 64 * 4);
  float* roi  = (float*)alloc((size_t)NA * 4 * 4);
  u64*   keys = (u64*)alloc((size_t)NSORT * 8);
  u64*   tmp  = (u64*)alloc((size_t)24576 * 8);
  u64*   topk = (u64*)alloc((size_t)TOPN * 8);
  u64*   valw = (u64*)alloc((size_t)NW * 8);
  u64*   MT   = (u64*)alloc((size_t)NW * MTS * 8);               // 4.52 MB

  hipMemsetAsync(d_out, 0, (size_t)out_size * 4, stream);

  prep_kernel<<<PB_END, 256, 0, stream>>>(x, xp, w1, wt, lw, sw, wt2, keys);
  conv_gemm_kernel<<<dim3(4, 15, KSPLIT), 256, 0, stream>>>(wt, xp, part);
  reduce_relu_kernel<<<(CIN * HW) / 256, 256, 0, stream>>>(part, b1, h1);
  heads_decode_kernel<<<30, 256, 0, stream>>>(wt2, h1, lb, sb, roi, keys);
  sort_kernel<<<5, 1024, 0, stream>>>(keys);
  merge1_kernel<<<dim3(2, 2), 256, 0, stream>>>(keys, tmp);
  merge2_kernel<<<2, 256, 0, stream>>>(tmp, tmp + 16384);
  merge3_kernel<<<2, 256, 0, stream>>>(tmp + 16384, keys, topk);
  mask_kernel<<<dim3(NW, 24), 256, 0, stream>>>(topk, roi, MT, valw);
  nms_scan_kernel<<<1, 64, 0, stream>>>(MT, valw, topk, roi, out);
}